// Round 3
// baseline (152.666 us; speedup 1.0000x reference)
//
#include <hip/hip_runtime.h>
#include <math.h>

// Problem constants
#define S_ 500
#define D_ 768
#define K_ 16
#define R_ 256
#define P_ 64

typedef unsigned short ushort_t;
typedef __attribute__((ext_vector_type(8))) short short8;   // 8 x bf16 (4 VGPRs)
typedef __attribute__((ext_vector_type(4))) float floatx4;  // MFMA accumulator

__device__ inline ushort_t f2bf(float x) {  // fp32 -> bf16, round-nearest-even
  unsigned int u = __float_as_uint(x);
  u += 0x7fffu + ((u >> 16) & 1u);
  return (ushort_t)(u >> 16);
}

#define GLD_LDS16(g, l)                                                        \
  __builtin_amdgcn_global_load_lds(                                            \
      (const __attribute__((address_space(1))) void*)(g),                      \
      (__attribute__((address_space(3))) void*)(l), 16, 0, 0)

// ---------------------------------------------------------------------------
// prep: fused convert_we + transpose_w.
//  blocks [0,384):    WE fp32 [500][768] -> WEb bf16 [512][768] (pad rows = 0)
//  blocks [384,2688): W fp32 [768][12288] -> Wt bf16 [12288][768] (64x64 tiles)
// ---------------------------------------------------------------------------
__global__ __launch_bounds__(256) void prep(const float* __restrict__ WE,
                                            const float* __restrict__ W,
                                            ushort_t* __restrict__ WEb,
                                            ushort_t* __restrict__ Wt) {
  const int t = threadIdx.x;
  if (blockIdx.x < 384) {
    int gid = blockIdx.x * 256 + t;  // 98304 threads, 4 elems each
    int row = gid / 192;             // 192 float4 per row
    ushort4 o = {0, 0, 0, 0};
    if (row < S_) {
      float4 v = *(const float4*)(WE + (size_t)gid * 4);
      o.x = f2bf(v.x); o.y = f2bf(v.y); o.z = f2bf(v.z); o.w = f2bf(v.w);
    }
    *(ushort4*)(WEb + (size_t)gid * 4) = o;
    return;
  }
  // ---- transpose tile (64 d) x (64 n) ----
  __shared__ float tile[64][68];
  const int tb = blockIdx.x - 384;          // 0..2303
  const int n0 = (tb % 192) * 64, d0 = (tb / 192) * 64;
  {
    const int r = t >> 2, cbase = (t & 3) * 16;  // row r, 4 float4 chunks
#pragma unroll
    for (int i = 0; i < 4; i++) {
      float4 v = *(const float4*)(W + (size_t)(d0 + r) * 12288 + n0 + cbase + i * 4);
      *(float4*)&tile[r][cbase + i * 4] = v;
    }
  }
  __syncthreads();
  {
    const int bc = t & 15;            // d sub-block (4 cols of output)
    const int br4 = (t >> 4) * 4;     // n sub-block (4 rows of output)
    float4 tv[4];
#pragma unroll
    for (int ii = 0; ii < 4; ii++)
      tv[ii] = *(const float4*)&tile[bc * 4 + ii][br4];  // 16B aligned (68%4==0)
#pragma unroll
    for (int j = 0; j < 4; j++) {
      ushort4 o;
      o.x = f2bf(((const float*)&tv[0])[j]);
      o.y = f2bf(((const float*)&tv[1])[j]);
      o.z = f2bf(((const float*)&tv[2])[j]);
      o.w = f2bf(((const float*)&tv[3])[j]);
      *(ushort4*)(Wt + (size_t)(n0 + br4 + j) * 768 + d0 + bc * 4) = o;
    }
  }
}

// ---------------------------------------------------------------------------
// mm_bt<MODE>: C[M][N] = A[M][768] * B[N][768]^T, bf16 in, fp32 MFMA accum.
// m97 structure: 128x128 tile, BK=32, 4 waves, global_load_lds width 16.
// MODE 0: mfma(b,a) -> lane regs span 4 consecutive C-cols -> ushort4 stores
//         C = proj bf16 [512][12288] (== proj2d [8192][768] in memory)
// MODE 1: mfma(a,b) -> lane regs span k (G's contiguous dim) -> float4 scatter
//         into G[s1][s2][16] (m=(s1,k), n=s2), guarded <500
// ---------------------------------------------------------------------------
template <int MODE>
__global__ __launch_bounds__(256) void mm_bt(const ushort_t* __restrict__ A,
                                             const ushort_t* __restrict__ Bm,
                                             void* __restrict__ Cout) {
  __shared__ ushort_t As[128 * 32];  // [row m][k] bf16, 8 KB
  __shared__ ushort_t Bs[128 * 32];  // [row n][k] bf16, 8 KB
  const int tid = threadIdx.x;
  const int wave = tid >> 6, lane = tid & 63;
  const int m0 = blockIdx.y * 128, n0 = blockIdx.x * 128;
  const int wm = (wave & 1) * 64, wn = (wave >> 1) * 64;  // wave's 64x64 quadrant
  const int col = lane & 15, quad = lane >> 4;

  floatx4 acc[4][4];
#pragma unroll
  for (int i = 0; i < 4; i++)
#pragma unroll
    for (int j = 0; j < 4; j++)
#pragma unroll
      for (int e = 0; e < 4; e++) acc[i][j][e] = 0.f;

  const int srow = wave * 32 + (lane >> 2);  // staging: 16 rows/issue, 2 issues
  const int scol = (lane & 3) * 8;           // 8 bf16 = 16 B per lane

  for (int k0 = 0; k0 < D_; k0 += 32) {
    const ushort_t* ga = A + (size_t)(m0 + srow) * D_ + k0 + scol;
    const ushort_t* gb = Bm + (size_t)(n0 + srow) * D_ + k0 + scol;
    __syncthreads();
    GLD_LDS16(ga, &As[(wave * 32) * 32]);
    GLD_LDS16(ga + 16 * D_, &As[(wave * 32 + 16) * 32]);
    GLD_LDS16(gb, &Bs[(wave * 32) * 32]);
    GLD_LDS16(gb + 16 * D_, &Bs[(wave * 32 + 16) * 32]);
    __syncthreads();

    short8 a[4], b[4];
#pragma unroll
    for (int i = 0; i < 4; i++)
      a[i] = *(const short8*)&As[(wm + i * 16 + col) * 32 + quad * 8];
#pragma unroll
    for (int j = 0; j < 4; j++)
      b[j] = *(const short8*)&Bs[(wn + j * 16 + col) * 32 + quad * 8];
#pragma unroll
    for (int i = 0; i < 4; i++)
#pragma unroll
      for (int j = 0; j < 4; j++) {
        if (MODE == 0)  // D[row=quad*4+reg -> n][col=lane&15 -> m]
          acc[i][j] = __builtin_amdgcn_mfma_f32_16x16x32_bf16(b[j], a[i], acc[i][j], 0, 0, 0);
        else            // D[row=quad*4+reg -> m][col=lane&15 -> n]
          acc[i][j] = __builtin_amdgcn_mfma_f32_16x16x32_bf16(a[i], b[j], acc[i][j], 0, 0, 0);
      }
  }

  if (MODE == 0) {
    // lane holds rows m = m0+wm+i*16+col, cols n0+wn+j*16+quad*4 .. +3
    ushort_t* C = (ushort_t*)Cout;
#pragma unroll
    for (int i = 0; i < 4; i++) {
      int m = m0 + wm + i * 16 + col;
#pragma unroll
      for (int j = 0; j < 4; j++) {
        int n = n0 + wn + j * 16 + quad * 4;
        ushort4 o;
        o.x = f2bf(acc[i][j][0]); o.y = f2bf(acc[i][j][1]);
        o.z = f2bf(acc[i][j][2]); o.w = f2bf(acc[i][j][3]);
        *(ushort4*)(C + (size_t)m * 12288 + n) = o;
      }
    }
  } else {
    // G[s1][s2][16] fp32: m = (s1,k); 16x16 m-tile is one s1, k = quad*4+reg
    float* G = (float*)Cout;
#pragma unroll
    for (int i = 0; i < 4; i++) {
      int s1 = (m0 + wm + i * 16) >> 4;
#pragma unroll
      for (int j = 0; j < 4; j++) {
        int s2 = n0 + wn + j * 16 + col;
        if (s1 < S_ && s2 < S_)
          *(floatx4*)(G + (((size_t)s1 * S_ + s2) << 4) + quad * 4) = acc[i][j];
      }
    }
  }
}

// ---------------------------------------------------------------------------
// lse_part: 4 blocks per r, each reduces a strided quarter of the (p,q) pairs
// to a partial (max, sum) per k. lse_combine merges the 4 partials.
// ---------------------------------------------------------------------------
__global__ __launch_bounds__(256) void lse_part(const float* __restrict__ G,
                                                const int* __restrict__ idx1,
                                                const int* __restrict__ idx2,
                                                const float* __restrict__ mask1,
                                                const float* __restrict__ mask2,
                                                float* __restrict__ pm,
                                                float* __restrict__ ps) {
  const int r = blockIdx.x >> 2, seg = blockIdx.x & 3;
  const int tid = threadIdx.x;
  __shared__ int b1[P_], b2[P_];
  __shared__ int s_len1, s_len2;
  __shared__ float wmx[4][K_], wsum[4][K_];

  if (tid < 64) {
    float mv = mask1[r * P_ + tid];
    unsigned long long bal = __ballot(mv > 0.5f);
    if (tid == 0) s_len1 = (int)__popcll(bal);
    b1[tid] = idx1[r * P_ + tid] * (S_ * K_);
  } else if (tid < 128) {
    int q = tid - 64;
    float mv = mask2[r * P_ + q];
    unsigned long long bal = __ballot(mv > 0.5f);
    if (q == 0) s_len2 = (int)__popcll(bal);
    b2[q] = idx2[r * P_ + q] * K_;
  }
  __syncthreads();
  const int len2 = s_len2;
  const int total = s_len1 * len2;

  float m[K_], s[K_];
#pragma unroll
  for (int k = 0; k < K_; k++) { m[k] = -3.0e38f; s[k] = 0.f; }

  for (int i = seg * 256 + tid; i < total; i += 1024) {
    int p = i / len2;
    int q = i - p * len2;
    const float4* g4 = (const float4*)(G + b1[p] + b2[q]);
    float4 z0 = g4[0], z1 = g4[1], z2 = g4[2], z3 = g4[3];
    float z[K_] = {z0.x, z0.y, z0.z, z0.w, z1.x, z1.y, z1.z, z1.w,
                   z2.x, z2.y, z2.z, z2.w, z3.x, z3.y, z3.z, z3.w};
#pragma unroll
    for (int k = 0; k < K_; k++) {
      float zk = z[k];
      float M2 = fmaxf(m[k], zk);
      s[k] = s[k] * __expf(m[k] - M2) + __expf(zk - M2);
      m[k] = M2;
    }
  }

#pragma unroll
  for (int off = 1; off < 64; off <<= 1) {
#pragma unroll
    for (int k = 0; k < K_; k++) {
      float mo = __shfl_xor(m[k], off, 64);
      float so = __shfl_xor(s[k], off, 64);
      float M2 = fmaxf(m[k], mo);
      s[k] = s[k] * __expf(m[k] - M2) + so * __expf(mo - M2);
      m[k] = M2;
    }
  }
  const int wave = tid >> 6, lane = tid & 63;
  if (lane == 0) {
#pragma unroll
    for (int k = 0; k < K_; k++) { wmx[wave][k] = m[k]; wsum[wave][k] = s[k]; }
  }
  __syncthreads();
  if (tid < K_) {
    float M = -3.0e38f, Ssum = 0.f;
#pragma unroll
    for (int w = 0; w < 4; w++) {
      float mo = wmx[w][tid], so = wsum[w][tid];
      float M2 = fmaxf(M, mo);
      Ssum = Ssum * __expf(M - M2) + so * __expf(mo - M2);
      M = M2;
    }
    pm[(r * 4 + seg) * K_ + tid] = M;
    ps[(r * 4 + seg) * K_ + tid] = Ssum;
  }
}

__global__ __launch_bounds__(256) void lse_combine(const float* __restrict__ pm,
                                                   const float* __restrict__ ps,
                                                   float* __restrict__ out) {
  int gid = blockIdx.x * 256 + threadIdx.x;  // 4096 = 256 r * 16 k
  int r = gid >> 4, k = gid & 15;
  float M = -3.0e38f, Ssum = 0.f;
#pragma unroll
  for (int seg = 0; seg < 4; seg++) {
    float mo = pm[(r * 4 + seg) * K_ + k];
    float so = ps[(r * 4 + seg) * K_ + k];
    float M2 = fmaxf(M, mo);
    Ssum = Ssum * __expf(M - M2) + so * __expf(mo - M2);
    M = M2;
  }
  out[gid] = M + __logf(Ssum);
}

// ---------------------------------------------------------------------------
extern "C" void kernel_launch(void* const* d_in, const int* in_sizes, int n_in,
                              void* d_out, int out_size, void* d_ws, size_t ws_size,
                              hipStream_t stream) {
  const float* WE    = (const float*)d_in[0];  // [500][768]
  const float* W     = (const float*)d_in[1];  // [768][16][768]
  const int*   idx1  = (const int*)d_in[2];
  const int*   idx2  = (const int*)d_in[3];
  const float* mask1 = (const float*)d_in[4];
  const float* mask2 = (const float*)d_in[5];
  float* out = (float*)d_out;                  // [256][16]

  // workspace: WEb [512][768] bf16 | Wt [12288][768] bf16 |
  //            projb [512][12288] bf16 (== [8192][768]) | G [500][500][16] f32 |
  //            pm/ps [256][4][16] f32
  ushort_t* WEb   = (ushort_t*)d_ws;
  ushort_t* Wt    = WEb + (size_t)512 * 768;
  ushort_t* projb = Wt + (size_t)12288 * 768;
  float*    G     = (float*)(projb + (size_t)8192 * 768);
  float*    pm    = G + (size_t)S_ * S_ * K_;
  float*    ps    = pm + R_ * 4 * K_;
  // total ~48.4 MB, 16B-aligned throughout

  prep<<<384 + 2304, 256, 0, stream>>>(WE, W, WEb, Wt);
  // proj[s][(k,e)] = WEb @ Wt^T : M=512, N=12288
  mm_bt<0><<<dim3(96, 4), 256, 0, stream>>>(WEb, Wt, (void*)projb);
  // G[(s1,k)][s2] = projb @ WEb^T : M=8192, N=512, scattered to [s1][s2][16]
  mm_bt<1><<<dim3(4, 64), 256, 0, stream>>>(projb, WEb, (void*)G);
  lse_part<<<R_ * 4, 256, 0, stream>>>(G, idx1, idx2, mask1, mask2, pm, ps);
  lse_combine<<<16, 256, 0, stream>>>(pm, ps, out);
}

// Round 4
// 143.763 us; speedup vs baseline: 1.0619x; 1.0619x over previous
//
#include <hip/hip_runtime.h>
#include <math.h>

// Problem constants
#define S_ 500
#define D_ 768
#define K_ 16
#define R_ 256
#define P_ 64
#define NT 12  // 768 / BK, BK = 64

typedef unsigned short ushort_t;
typedef __attribute__((ext_vector_type(8))) short short8;   // 8 x bf16 (4 VGPRs)
typedef __attribute__((ext_vector_type(4))) float floatx4;  // MFMA accumulator

__device__ inline ushort_t f2bf(float x) {  // fp32 -> bf16, round-nearest-even
  unsigned int u = __float_as_uint(x);
  u += 0x7fffu + ((u >> 16) & 1u);
  return (ushort_t)(u >> 16);
}

#define GLD_LDS16(g, l)                                                        \
  __builtin_amdgcn_global_load_lds(                                            \
      (const __attribute__((address_space(1))) void*)(g),                      \
      (__attribute__((address_space(3))) void*)(l), 16, 0, 0)

// raw barrier / fine-grained vmcnt: no compiler-inserted vmcnt(0) drain.
#define ASM_BARRIER asm volatile("s_barrier" ::: "memory")
#define WAIT_VM8 asm volatile("s_waitcnt vmcnt(8)" ::: "memory")
#define WAIT_VM0 asm volatile("s_waitcnt vmcnt(0)" ::: "memory")

// ---------------------------------------------------------------------------
// prep: fused convert_we + transpose_w.
//  blocks [0,384):    WE fp32 [500][768] -> WEb bf16 [512][768] (pad rows = 0)
//  blocks [384,2688): W fp32 [768][12288] -> Wt bf16 [12288][768] (64x64 tiles)
// ---------------------------------------------------------------------------
__global__ __launch_bounds__(256) void prep(const float* __restrict__ WE,
                                            const float* __restrict__ W,
                                            ushort_t* __restrict__ WEb,
                                            ushort_t* __restrict__ Wt) {
  const int t = threadIdx.x;
  if (blockIdx.x < 384) {
    int gid = blockIdx.x * 256 + t;  // 98304 threads, 4 elems each
    int row = gid / 192;             // 192 float4 per row
    ushort4 o = {0, 0, 0, 0};
    if (row < S_) {
      float4 v = *(const float4*)(WE + (size_t)gid * 4);
      o.x = f2bf(v.x); o.y = f2bf(v.y); o.z = f2bf(v.z); o.w = f2bf(v.w);
    }
    *(ushort4*)(WEb + (size_t)gid * 4) = o;
    return;
  }
  __shared__ float tile[64][68];
  const int tb = blockIdx.x - 384;          // 0..2303
  const int n0 = (tb % 192) * 64, d0 = (tb / 192) * 64;
  {
    const int r = t >> 2, cbase = (t & 3) * 16;
#pragma unroll
    for (int i = 0; i < 4; i++) {
      float4 v = *(const float4*)(W + (size_t)(d0 + r) * 12288 + n0 + cbase + i * 4);
      *(float4*)&tile[r][cbase + i * 4] = v;
    }
  }
  __syncthreads();
  {
    const int bc = t & 15;
    const int br4 = (t >> 4) * 4;
    float4 tv[4];
#pragma unroll
    for (int ii = 0; ii < 4; ii++)
      tv[ii] = *(const float4*)&tile[bc * 4 + ii][br4];
#pragma unroll
    for (int j = 0; j < 4; j++) {
      ushort4 o;
      o.x = f2bf(((const float*)&tv[0])[j]);
      o.y = f2bf(((const float*)&tv[1])[j]);
      o.z = f2bf(((const float*)&tv[2])[j]);
      o.w = f2bf(((const float*)&tv[3])[j]);
      *(ushort4*)(Wt + (size_t)(n0 + br4 + j) * 768 + d0 + bc * 4) = o;
    }
  }
}

// ---------------------------------------------------------------------------
// mm_bt<MODE>: C[M][N] = A[M][768] * B[N][768]^T, bf16 in, fp32 MFMA accum.
// 128x128 tile, BK=64 (2 x 32-k sub-buffers, m97 64B row stride), explicit
// LDS double-buffer: tile t+1's global_load_lds stays in flight across
// compute(t); raw s_barrier + vmcnt(8) — never a full drain mid-loop.
// MODE 0: mfma(b,a) -> lane regs span 4 consecutive C-cols -> ushort4 stores
//         C = proj bf16 [512][12288] (== proj2d [8192][768] in memory)
// MODE 1: mfma(a,b) -> lane regs span k (G's contiguous dim) -> ushort4
//         scatter into bf16 G[s1][s2][16] (m=(s1,k), n=s2), guarded <500
// ---------------------------------------------------------------------------
template <int MODE>
__global__ __launch_bounds__(256) void mm_bt(const ushort_t* __restrict__ A,
                                             const ushort_t* __restrict__ Bm,
                                             void* __restrict__ Cout) {
  __shared__ ushort_t As[2][2][128 * 32];  // [buf][sub][row][32k], 32 KB
  __shared__ ushort_t Bs[2][2][128 * 32];  // 32 KB
  const int tid = threadIdx.x;
  const int wave = tid >> 6, lane = tid & 63;
  const int m0 = blockIdx.y * 128, n0 = blockIdx.x * 128;
  const int wm = (wave & 1) * 64, wn = (wave >> 1) * 64;
  const int col = lane & 15, quad = lane >> 4;

  floatx4 acc[4][4];
#pragma unroll
  for (int i = 0; i < 4; i++)
#pragma unroll
    for (int j = 0; j < 4; j++)
#pragma unroll
      for (int e = 0; e < 4; e++) acc[i][j][e] = 0.f;

  // staging: per sub-buffer, wave fills rows [wave*32, +32): 2 issues x 16 rows
  const int srow = wave * 32 + (lane >> 2);
  const int scol = (lane & 3) * 8;  // 8 bf16 = 16 B
  const ushort_t* ga0 = A + (size_t)(m0 + srow) * D_ + scol;
  const ushort_t* gb0 = Bm + (size_t)(n0 + srow) * D_ + scol;
  const int ldsbase = (wave * 32) * 32;

#define ISSUE_TILE(t_, buf_)                                                   \
  do {                                                                         \
    const ushort_t* ga = ga0 + (t_)*64;                                        \
    const ushort_t* gb = gb0 + (t_)*64;                                        \
    GLD_LDS16(ga, &As[buf_][0][ldsbase]);                                      \
    GLD_LDS16(ga + 16 * D_, &As[buf_][0][ldsbase + 16 * 32]);                  \
    GLD_LDS16(ga + 32, &As[buf_][1][ldsbase]);                                 \
    GLD_LDS16(ga + 32 + 16 * D_, &As[buf_][1][ldsbase + 16 * 32]);             \
    GLD_LDS16(gb, &Bs[buf_][0][ldsbase]);                                      \
    GLD_LDS16(gb + 16 * D_, &Bs[buf_][0][ldsbase + 16 * 32]);                  \
    GLD_LDS16(gb + 32, &Bs[buf_][1][ldsbase]);                                 \
    GLD_LDS16(gb + 32 + 16 * D_, &Bs[buf_][1][ldsbase + 16 * 32]);             \
  } while (0)

  ISSUE_TILE(0, 0);
  for (int t = 0; t < NT; ++t) {
    const int cur = t & 1;
    if (t + 1 < NT) {
      ISSUE_TILE(t + 1, cur ^ 1);
      WAIT_VM8;  // my 8 loads for tile t retired; t+1's stay in flight
    } else {
      WAIT_VM0;
    }
    ASM_BARRIER;  // all waves' tile-t loads visible
#pragma unroll
    for (int s = 0; s < 2; ++s) {
      short8 a[4], b[4];
#pragma unroll
      for (int i = 0; i < 4; i++)
        a[i] = *(const short8*)&As[cur][s][(wm + i * 16 + col) * 32 + quad * 8];
#pragma unroll
      for (int j = 0; j < 4; j++)
        b[j] = *(const short8*)&Bs[cur][s][(wn + j * 16 + col) * 32 + quad * 8];
#pragma unroll
      for (int i = 0; i < 4; i++)
#pragma unroll
        for (int j = 0; j < 4; j++) {
          if (MODE == 0)
            acc[i][j] = __builtin_amdgcn_mfma_f32_16x16x32_bf16(b[j], a[i], acc[i][j], 0, 0, 0);
          else
            acc[i][j] = __builtin_amdgcn_mfma_f32_16x16x32_bf16(a[i], b[j], acc[i][j], 0, 0, 0);
        }
    }
    ASM_BARRIER;  // all waves done reading buf[cur]; t+1 may overwrite it
  }
#undef ISSUE_TILE

  if (MODE == 0) {
    // lane holds rows m = m0+wm+i*16+col, cols n0+wn+j*16+quad*4 .. +3
    ushort_t* C = (ushort_t*)Cout;
#pragma unroll
    for (int i = 0; i < 4; i++) {
      int m = m0 + wm + i * 16 + col;
#pragma unroll
      for (int j = 0; j < 4; j++) {
        int n = n0 + wn + j * 16 + quad * 4;
        ushort4 o;
        o.x = f2bf(acc[i][j][0]); o.y = f2bf(acc[i][j][1]);
        o.z = f2bf(acc[i][j][2]); o.w = f2bf(acc[i][j][3]);
        *(ushort4*)(C + (size_t)m * 12288 + n) = o;
      }
    }
  } else {
    // G[s1][s2][16] bf16: m = (s1,k); 16x16 m-tile is one s1, k = quad*4+reg
    ushort_t* G = (ushort_t*)Cout;
#pragma unroll
    for (int i = 0; i < 4; i++) {
      int s1 = (m0 + wm + i * 16) >> 4;
#pragma unroll
      for (int j = 0; j < 4; j++) {
        int s2 = n0 + wn + j * 16 + col;
        if (s1 < S_ && s2 < S_) {
          ushort4 o;
          o.x = f2bf(acc[i][j][0]); o.y = f2bf(acc[i][j][1]);
          o.z = f2bf(acc[i][j][2]); o.w = f2bf(acc[i][j][3]);
          *(ushort4*)(G + (((size_t)s1 * S_ + s2) << 4) + quad * 4) = o;
        }
      }
    }
  }
}

// ---------------------------------------------------------------------------
// lse_part: 4 blocks per r, strided quarter of (p,q) pairs -> partial (max,sum)
// per k (G is bf16). lse_combine merges the 4 partials.
// ---------------------------------------------------------------------------
__global__ __launch_bounds__(256) void lse_part(const ushort_t* __restrict__ G,
                                                const int* __restrict__ idx1,
                                                const int* __restrict__ idx2,
                                                const float* __restrict__ mask1,
                                                const float* __restrict__ mask2,
                                                float* __restrict__ pm,
                                                float* __restrict__ ps) {
  const int r = blockIdx.x >> 2, seg = blockIdx.x & 3;
  const int tid = threadIdx.x;
  __shared__ int b1[P_], b2[P_];
  __shared__ int s_len1, s_len2;
  __shared__ float wmx[4][K_], wsum[4][K_];

  if (tid < 64) {
    float mv = mask1[r * P_ + tid];
    unsigned long long bal = __ballot(mv > 0.5f);
    if (tid == 0) s_len1 = (int)__popcll(bal);
    b1[tid] = idx1[r * P_ + tid] * (S_ * K_);
  } else if (tid < 128) {
    int q = tid - 64;
    float mv = mask2[r * P_ + q];
    unsigned long long bal = __ballot(mv > 0.5f);
    if (q == 0) s_len2 = (int)__popcll(bal);
    b2[q] = idx2[r * P_ + q] * K_;
  }
  __syncthreads();
  const int len2 = s_len2;
  const int total = s_len1 * len2;

  float m[K_], s[K_];
#pragma unroll
  for (int k = 0; k < K_; k++) { m[k] = -3.0e38f; s[k] = 0.f; }

  for (int i = seg * 256 + tid; i < total; i += 1024) {
    int p = i / len2;
    int q = i - p * len2;
    const uint4* g4 = (const uint4*)(G + b1[p] + b2[q]);  // 16 bf16 = 32 B
    uint4 w0 = g4[0], w1 = g4[1];
    unsigned int uu[8] = {w0.x, w0.y, w0.z, w0.w, w1.x, w1.y, w1.z, w1.w};
    float z[K_];
#pragma unroll
    for (int h = 0; h < 8; h++) {
      z[2 * h + 0] = __uint_as_float(uu[h] << 16);
      z[2 * h + 1] = __uint_as_float(uu[h] & 0xffff0000u);
    }
#pragma unroll
    for (int k = 0; k < K_; k++) {
      float zk = z[k];
      float M2 = fmaxf(m[k], zk);
      s[k] = s[k] * __expf(m[k] - M2) + __expf(zk - M2);
      m[k] = M2;
    }
  }

#pragma unroll
  for (int off = 1; off < 64; off <<= 1) {
#pragma unroll
    for (int k = 0; k < K_; k++) {
      float mo = __shfl_xor(m[k], off, 64);
      float so = __shfl_xor(s[k], off, 64);
      float M2 = fmaxf(m[k], mo);
      s[k] = s[k] * __expf(m[k] - M2) + so * __expf(mo - M2);
      m[k] = M2;
    }
  }
  const int wave = tid >> 6, lane = tid & 63;
  if (lane == 0) {
#pragma unroll
    for (int k = 0; k < K_; k++) { wmx[wave][k] = m[k]; wsum[wave][k] = s[k]; }
  }
  __syncthreads();
  if (tid < K_) {
    float M = -3.0e38f, Ssum = 0.f;
#pragma unroll
    for (int w = 0; w < 4; w++) {
      float mo = wmx[w][tid], so = wsum[w][tid];
      float M2 = fmaxf(M, mo);
      Ssum = Ssum * __expf(M - M2) + so * __expf(mo - M2);
      M = M2;
    }
    pm[(r * 4 + seg) * K_ + tid] = M;
    ps[(r * 4 + seg) * K_ + tid] = Ssum;
  }
}

__global__ __launch_bounds__(256) void lse_combine(const float* __restrict__ pm,
                                                   const float* __restrict__ ps,
                                                   float* __restrict__ out) {
  int gid = blockIdx.x * 256 + threadIdx.x;  // 4096 = 256 r * 16 k
  int r = gid >> 4, k = gid & 15;
  float M = -3.0e38f, Ssum = 0.f;
#pragma unroll
  for (int seg = 0; seg < 4; seg++) {
    float mo = pm[(r * 4 + seg) * K_ + k];
    float so = ps[(r * 4 + seg) * K_ + k];
    float M2 = fmaxf(M, mo);
    Ssum = Ssum * __expf(M - M2) + so * __expf(mo - M2);
    M = M2;
  }
  out[gid] = M + __logf(Ssum);
}

// ---------------------------------------------------------------------------
extern "C" void kernel_launch(void* const* d_in, const int* in_sizes, int n_in,
                              void* d_out, int out_size, void* d_ws, size_t ws_size,
                              hipStream_t stream) {
  const float* WE    = (const float*)d_in[0];  // [500][768]
  const float* W     = (const float*)d_in[1];  // [768][16][768]
  const int*   idx1  = (const int*)d_in[2];
  const int*   idx2  = (const int*)d_in[3];
  const float* mask1 = (const float*)d_in[4];
  const float* mask2 = (const float*)d_in[5];
  float* out = (float*)d_out;                  // [256][16]

  // workspace: WEb [512][768] bf16 | Wt [12288][768] bf16 |
  //            projb [512][12288] bf16 (== [8192][768]) | G [500][500][16] bf16 |
  //            pm/ps [256][4][16] f32
  ushort_t* WEb   = (ushort_t*)d_ws;
  ushort_t* Wt    = WEb + (size_t)512 * 768;
  ushort_t* projb = Wt + (size_t)12288 * 768;
  ushort_t* G     = projb + (size_t)8192 * 768;
  float*    pm    = (float*)(G + (size_t)S_ * S_ * K_);
  float*    ps    = pm + R_ * 4 * K_;
  // total ~40.4 MB, 16B-aligned throughout

  prep<<<384 + 2304, 256, 0, stream>>>(WE, W, WEb, Wt);
  // proj[s][(k,e)] = WEb @ Wt^T : M=512, N=12288
  mm_bt<0><<<dim3(96, 4), 256, 0, stream>>>(WEb, Wt, (void*)projb);
  // G[(s1,k)][s2] = projb @ WEb^T : M=8192, N=512, scattered to [s1][s2][k] bf16
  mm_bt<1><<<dim3(4, 64), 256, 0, stream>>>(projb, WEb, (void*)G);
  lse_part<<<R_ * 4, 256, 0, stream>>>(G, idx1, idx2, mask1, mask2, pm, ps);
  lse_combine<<<16, 256, 0, stream>>>(pm, ps, out);
}